// Round 4
// baseline (1047.049 us; speedup 1.0000x reference)
//
#include <hip/hip_runtime.h>
#include <hip/hip_bf16.h>
#include <stdint.h>

// Problem constants
#define BB   8192   // batch
#define DD   8      // features
#define PP   10     // poly basis width
#define RR   512    // TT rank
#define OUTD 64     // output dim
#define KK   5120   // expanded K = PP*RR (j-major: kk = j*512 + i)

typedef __bf16 bf16x8 __attribute__((ext_vector_type(8)));
typedef float  f32x4  __attribute__((ext_vector_type(4)));

__device__ __forceinline__ void gload_lds16(const __hip_bfloat16* g, __hip_bfloat16* l) {
    __builtin_amdgcn_global_load_lds(
        (const __attribute__((address_space(1))) void*)g,
        (__attribute__((address_space(3))) void*)l, 16, 0, 0);
}

// ---------------------------------------------------------------------------
// Prep: tanh + transpose G_mid[c][i][j][k] -> tB[c][k][j*512 + i]  (bf16)
// ---------------------------------------------------------------------------
__global__ __launch_bounds__(256) void tanh_transpose_mid(
        const float* __restrict__ G, __hip_bfloat16* __restrict__ tB) {
    __shared__ float t[32][33];
    const int cj = blockIdx.z;
    const int c  = cj / 10, j = cj % 10;
    const int i0 = blockIdx.x * 32, k0 = blockIdx.y * 32;
    const float* src = G + (size_t)c * (RR * PP * RR) + (size_t)j * RR;
    #pragma unroll
    for (int q = 0; q < 4; ++q) {
        int i = i0 + threadIdx.y + q * 8;
        int k = k0 + threadIdx.x;
        t[threadIdx.y + q * 8][threadIdx.x] = src[(size_t)i * (PP * RR) + k];
    }
    __syncthreads();
    __hip_bfloat16* dst = tB + (size_t)c * (RR * KK) + (size_t)j * RR;
    #pragma unroll
    for (int q = 0; q < 4; ++q) {
        int k = k0 + threadIdx.y + q * 8;
        int i = i0 + threadIdx.x;
        dst[(size_t)k * KK + i] = __float2bfloat16(tanhf(t[threadIdx.x][threadIdx.y + q * 8]));
    }
}

// ---------------------------------------------------------------------------
// Prep: tanh + transpose G_last[i][j][l] -> tB[l][j*512 + i]  (bf16)
// ---------------------------------------------------------------------------
__global__ __launch_bounds__(256) void tanh_transpose_last(
        const float* __restrict__ G, __hip_bfloat16* __restrict__ tB) {
    __shared__ float t[32][33];
    const int j  = blockIdx.z;
    const int i0 = blockIdx.x * 32, l0 = blockIdx.y * 32;
    #pragma unroll
    for (int q = 0; q < 4; ++q) {
        int i = i0 + threadIdx.y + q * 8;
        int l = l0 + threadIdx.x;
        t[threadIdx.y + q * 8][threadIdx.x] = G[(size_t)i * (PP * OUTD) + (size_t)j * OUTD + l];
    }
    __syncthreads();
    #pragma unroll
    for (int q = 0; q < 4; ++q) {
        int l = l0 + threadIdx.y + q * 8;
        int i = i0 + threadIdx.x;
        tB[(size_t)l * KK + (size_t)j * RR + i] =
            __float2bfloat16(tanhf(t[threadIdx.x][threadIdx.y + q * 8]));
    }
}

// ---------------------------------------------------------------------------
// First core: res0[b,r] = sum_j tanh(G0[j,r]) * z[b,0]^j  -> bf16
// ---------------------------------------------------------------------------
__global__ __launch_bounds__(512) void tt_first(
        const float* __restrict__ z, const float* __restrict__ G0,
        __hip_bfloat16* __restrict__ res0) {
    __shared__ float sg[PP * RR];
    const int b = blockIdx.x;
    for (int x = threadIdx.x; x < PP * RR; x += 512) sg[x] = tanhf(G0[x]);
    __syncthreads();
    const float z0 = z[(size_t)b * DD + 0];
    const int r = threadIdx.x;
    float p = 1.0f, acc = 0.0f;
    #pragma unroll
    for (int j = 0; j < PP; ++j) { acc += sg[j * RR + r] * p; p *= z0; }
    res0[(size_t)b * RR + r] = __float2bfloat16(acc);
}

// ---------------------------------------------------------------------------
// Mid-core Horner GEMM, A resident in registers, PROVEN 2-barrier K-loop.
//   grid 512 (1D): n_blk = bid & 3 (XCD-local B-column), m_blk = bid >> 2.
//   256 threads = 4 waves, wave tile 32x64 (2x2 over 64x128 block tile).
//   Each wave loads its 32x512 A-panel ONCE into 128 VGPRs. Horner over
//   j = 9..0: per K-tile stage B (16KB) -> sync -> ds_read+MFMA -> sync.
//   acc *= z_b between panels. Epilogue writes bf16 directly.
// ---------------------------------------------------------------------------
__global__ __launch_bounds__(256, 2) void tt_gemm_ar(
        const __hip_bfloat16* __restrict__ resin,   // [8192][512] bf16
        const __hip_bfloat16* __restrict__ tB,      // [512][5120] bf16 (n-major)
        __hip_bfloat16* __restrict__ resout,        // [8192][512] bf16
        const float* __restrict__ z, int d) {
    __shared__ __hip_bfloat16 sB[128 * 64];   // 16 KB

    const int tid  = threadIdx.x;
    const int lane = tid & 63;
    const int wave = tid >> 6;
    const int bid  = blockIdx.x;
    const int n0 = (bid & 3) * 128;
    const int m0 = (bid >> 2) * 64;
    const int wm = (wave >> 1) * 32;
    const int wn = (wave & 1) * 64;
    const int r16  = lane & 15;
    const int quad = lane >> 4;

    // ---- A resident in VGPRs: a[sm*16 + t*2 + ks] (frag layout) ----
    bf16x8 a[32];
    #pragma unroll
    for (int sm = 0; sm < 2; ++sm)
        #pragma unroll
        for (int t2 = 0; t2 < 16; ++t2)
            a[sm * 16 + t2] = *(const bf16x8*)(
                resin + (size_t)(m0 + wm + sm * 16 + r16) * RR + t2 * 32 + quad * 8);

    // ---- per-lane Horner row scales (C/D rows: wm + sm*16 + quad*4 + r) ----
    float zr[8];
    #pragma unroll
    for (int sm = 0; sm < 2; ++sm)
        #pragma unroll
        for (int r = 0; r < 4; ++r)
            zr[sm * 4 + r] = z[(size_t)(m0 + wm + sm * 16 + quad * 4 + r) * DD + d];

    f32x4 acc[2][4];
    #pragma unroll
    for (int sm = 0; sm < 2; ++sm)
        #pragma unroll
        for (int sn = 0; sn < 4; ++sn) acc[sm][sn] = f32x4{0.f, 0.f, 0.f, 0.f};

    // staging lane roles (swizzle verified 0-conflict in rounds 1-2)
    const int asrow = lane >> 3;
    const int acsw  = ((lane & 7) ^ asrow) * 8;

    #pragma unroll 1
    for (int p = 0; p < 10; ++p) {
        const int j = 9 - p;
        if (p) {
            #pragma unroll
            for (int sm = 0; sm < 2; ++sm)
                #pragma unroll
                for (int sn = 0; sn < 4; ++sn)
                    #pragma unroll
                    for (int r = 0; r < 4; ++r)
                        acc[sm][sn][r] *= zr[sm * 4 + r];
        }
        #pragma unroll 1
        for (int t = 0; t < 8; ++t) {
            const size_t koff = (size_t)j * RR + t * 64;
            // ---- stage B tile: 16 chunks of 8 rows x 128B, 4 per wave ----
            #pragma unroll
            for (int q = 0; q < 4; ++q) {
                const int c = wave * 4 + q;
                gload_lds16(tB + (size_t)(n0 + c * 8 + asrow) * KK + koff + acsw,
                            sB + c * 512 + lane * 8);
            }
            __syncthreads();
            // ---- compute: 2 K32 steps, A from registers ----
            #pragma unroll
            for (int ks = 0; ks < 2; ++ks) {
                const int q4 = ks * 4 + quad;
                bf16x8 bv[4];
                #pragma unroll
                for (int sn = 0; sn < 4; ++sn) {
                    const int row = wn + sn * 16 + r16;
                    bv[sn] = *(const bf16x8*)(sB + row * 64 + ((q4 ^ (row & 7)) << 3));
                }
                #pragma unroll
                for (int sm = 0; sm < 2; ++sm)
                    #pragma unroll
                    for (int sn = 0; sn < 4; ++sn)
                        acc[sm][sn] = __builtin_amdgcn_mfma_f32_16x16x32_bf16(
                            a[sm * 16 + t * 2 + ks], bv[sn], acc[sm][sn], 0, 0, 0);
            }
            __syncthreads();
        }
    }

    // ---- epilogue: bf16 store, C/D layout col=lane&15, row=quad*4+reg ----
    #pragma unroll
    for (int sm = 0; sm < 2; ++sm)
        #pragma unroll
        for (int sn = 0; sn < 4; ++sn)
            #pragma unroll
            for (int r = 0; r < 4; ++r)
                resout[(size_t)(m0 + wm + sm * 16 + quad * 4 + r) * RR
                       + n0 + wn + sn * 16 + r16] = __float2bfloat16(acc[sm][sn][r]);
}

// ---------------------------------------------------------------------------
// Last core (N=64): j-split GEMM, partial per j, epilogue scales by zb^j.
// grid (10, 64): x = j, BN=64, single panel. (Round-2 verified structure.)
// ---------------------------------------------------------------------------
template <int BN, int NPAN, bool LAST>
__global__ __launch_bounds__(256, 2) void tt_gemm_h(
        const __hip_bfloat16* __restrict__ resin,
        const __hip_bfloat16* __restrict__ tB,
        float* __restrict__ outp,
        const float* __restrict__ z, int d) {
    constexpr int BM = 128, BK = 64;
    constexpr int SN = BN / 32;
    constexpr int BCPW = (BN / 8) / 4;

    __shared__ __hip_bfloat16 sA[BM * BK];
    __shared__ __hip_bfloat16 sB[BN * BK];

    const int tid  = threadIdx.x;
    const int lane = tid & 63;
    const int wave = tid >> 6;
    const int m0 = blockIdx.y * BM;

    int n0, jtop, jbot;
    if (LAST) {
        n0 = 0; jtop = jbot = blockIdx.x;
        outp += (size_t)blockIdx.x * ((size_t)BB * OUTD);
    } else {
        n0 = (blockIdx.x >> 1) * BN;
        const int s = blockIdx.x & 1;
        jtop = 8 + s; jbot = s;
        outp += (size_t)s * ((size_t)BB * RR);
    }

    const int wm = (wave >> 1) * 64;
    const int wn = (wave & 1) * (BN / 2);
    const int rq = (lane >> 4) * 4;

    const int asrow = lane >> 3;
    const int acswz = ((lane & 7) ^ asrow) * 8;

    f32x4 acc[4][SN];
    #pragma unroll
    for (int a = 0; a < 4; ++a)
        #pragma unroll
        for (int b = 0; b < SN; ++b) acc[a][b] = f32x4{0.f, 0.f, 0.f, 0.f};

    #pragma unroll 1
    for (int pan = 0; pan < NPAN; ++pan) {
        const int j = jtop - 2 * pan;
        const size_t kb0 = (size_t)j * RR;

        #pragma unroll 1
        for (int kt = 0; kt < 8; ++kt) {
            const int kc = kt * 64;
            #pragma unroll
            for (int q = 0; q < 4; ++q) {
                const int ch = wave * 4 + q;
                gload_lds16(resin + (size_t)(m0 + ch * 8 + asrow) * RR + kc + acswz,
                            sA + ch * 512 + lane * 8);
            }
            #pragma unroll
            for (int q = 0; q < BCPW; ++q) {
                const int ch = wave * BCPW + q;
                gload_lds16(tB + (size_t)(n0 + ch * 8 + asrow) * KK + kb0 + kc + acswz,
                            sB + ch * 512 + lane * 8);
            }
            __syncthreads();

            #pragma unroll
            for (int ks = 0; ks < 2; ++ks) {
                const int q4 = ks * 4 + (lane >> 4);
                bf16x8 av[4], bv[SN];
                #pragma unroll
                for (int s = 0; s < 4; ++s) {
                    const int row = wm + s * 16 + (lane & 15);
                    av[s] = *(const bf16x8*)(sA + row * 64 + ((q4 ^ (row & 7)) << 3));
                }
                #pragma unroll
                for (int s = 0; s < SN; ++s) {
                    const int row = wn + s * 16 + (lane & 15);
                    bv[s] = *(const bf16x8*)(sB + row * 64 + ((q4 ^ (row & 7)) << 3));
                }
                #pragma unroll
                for (int sm = 0; sm < 4; ++sm)
                    #pragma unroll
                    for (int sn = 0; sn < SN; ++sn)
                        acc[sm][sn] = __builtin_amdgcn_mfma_f32_16x16x32_bf16(
                            av[sm], bv[sn], acc[sm][sn], 0, 0, 0);
            }
            __syncthreads();
        }
    }

    const int col = lane & 15;
    #pragma unroll
    for (int sm = 0; sm < 4; ++sm) {
        float zsc[4];
        #pragma unroll
        for (int r = 0; r < 4; ++r) {
            const int row = m0 + wm + sm * 16 + rq + r;
            const float zb = z[(size_t)row * DD + d];
            float p = 1.0f;
            for (int t = 0; t < jbot; ++t) p *= zb;
            zsc[r] = p;
        }
        #pragma unroll
        for (int sn = 0; sn < SN; ++sn)
            #pragma unroll
            for (int r = 0; r < 4; ++r) {
                const int grow = m0 + wm + sm * 16 + rq + r;
                const int gcol = n0 + wn + sn * 16 + col;
                outp[(size_t)grow * (LAST ? OUTD : RR) + gcol] = acc[sm][sn][r] * zsc[r];
            }
    }
}

// ---------------------------------------------------------------------------
// out[b,l] = sum_{s<10} parts[s][b][l]
// ---------------------------------------------------------------------------
__global__ __launch_bounds__(256) void reduce10(
        const float* __restrict__ p, float* __restrict__ o) {
    const size_t i = ((size_t)blockIdx.x * 256 + threadIdx.x) * 4;
    f32x4 s = f32x4{0.f, 0.f, 0.f, 0.f};
    #pragma unroll
    for (int q = 0; q < 10; ++q)
        s += *(const f32x4*)(p + (size_t)q * (BB * OUTD) + i);
    *(f32x4*)(o + i) = s;
}

// ---------------------------------------------------------------------------
extern "C" void kernel_launch(void* const* d_in, const int* in_sizes, int n_in,
                              void* d_out, int out_size, void* d_ws, size_t ws_size,
                              hipStream_t stream) {
    const float* z     = (const float*)d_in[0];
    const float* G0    = (const float*)d_in[1];
    const float* Gmid  = (const float*)d_in[2];
    const float* Glast = (const float*)d_in[3];
    float* out = (float*)d_out;

    char* ws = (char*)d_ws;
    __hip_bfloat16* resX = (__hip_bfloat16*)ws;                          // 8 MB
    __hip_bfloat16* resY = (__hip_bfloat16*)(ws + ((size_t)8 << 20));    // 8 MB
    float* LP            = (float*)(ws + ((size_t)16 << 20));            // 20 MB (last partials)
    __hip_bfloat16* tBmid  = (__hip_bfloat16*)(ws + ((size_t)48 << 20)); // 31.5 MB
    __hip_bfloat16* tBlast = (__hip_bfloat16*)(ws + ((size_t)80 << 20)); // 0.64 MB

    tanh_transpose_mid <<<dim3(16, 16, 60), dim3(32, 8), 0, stream>>>(Gmid,  tBmid);
    tanh_transpose_last<<<dim3(16, 2, 10),  dim3(32, 8), 0, stream>>>(Glast, tBlast);
    tt_first<<<BB, 512, 0, stream>>>(z, G0, resX);

    __hip_bfloat16* rin = resX;
    __hip_bfloat16* rnext = resY;
    for (int c = 0; c < 6; ++c) {
        tt_gemm_ar<<<dim3(512), 256, 0, stream>>>(
            rin, tBmid + (size_t)c * RR * KK, rnext, z, c + 1);
        __hip_bfloat16* t = rin; rin = rnext; rnext = t;
    }
    tt_gemm_h<64, 1, true><<<dim3(10, BB / 128), 256, 0, stream>>>(
        rin, tBlast, LP, z, 7);
    reduce10<<<dim3((BB * OUTD) / 1024), 256, 0, stream>>>(LP, out);
}

// Round 5
// 512.532 us; speedup vs baseline: 2.0429x; 2.0429x over previous
//
#include <hip/hip_runtime.h>
#include <hip/hip_bf16.h>
#include <stdint.h>

// Problem constants
#define BB   8192   // batch
#define DD   8      // features
#define PP   10     // poly basis width
#define RR   512    // TT rank
#define OUTD 64     // output dim
#define KK   5120   // expanded K = PP*RR (j-major: kk = j*512 + i)

typedef __bf16 bf16x8 __attribute__((ext_vector_type(8)));
typedef float  f32x4  __attribute__((ext_vector_type(4)));

__device__ __forceinline__ void gload_lds16(const __hip_bfloat16* g, __hip_bfloat16* l) {
    __builtin_amdgcn_global_load_lds(
        (const __attribute__((address_space(1))) void*)g,
        (__attribute__((address_space(3))) void*)l, 16, 0, 0);
}

// ---------------------------------------------------------------------------
// Prep: tanh + transpose G_mid[c][i][j][k] -> tB[c][k][j*512 + i]  (bf16)
// ---------------------------------------------------------------------------
__global__ __launch_bounds__(256) void tanh_transpose_mid(
        const float* __restrict__ G, __hip_bfloat16* __restrict__ tB) {
    __shared__ float t[32][33];
    const int cj = blockIdx.z;
    const int c  = cj / 10, j = cj % 10;
    const int i0 = blockIdx.x * 32, k0 = blockIdx.y * 32;
    const float* src = G + (size_t)c * (RR * PP * RR) + (size_t)j * RR;
    #pragma unroll
    for (int q = 0; q < 4; ++q) {
        int i = i0 + threadIdx.y + q * 8;
        int k = k0 + threadIdx.x;
        t[threadIdx.y + q * 8][threadIdx.x] = src[(size_t)i * (PP * RR) + k];
    }
    __syncthreads();
    __hip_bfloat16* dst = tB + (size_t)c * (RR * KK) + (size_t)j * RR;
    #pragma unroll
    for (int q = 0; q < 4; ++q) {
        int k = k0 + threadIdx.y + q * 8;
        int i = i0 + threadIdx.x;
        dst[(size_t)k * KK + i] = __float2bfloat16(tanhf(t[threadIdx.x][threadIdx.y + q * 8]));
    }
}

// ---------------------------------------------------------------------------
// Prep: tanh + transpose G_last[i][j][l] -> tB[l][j*512 + i]  (bf16)
// ---------------------------------------------------------------------------
__global__ __launch_bounds__(256) void tanh_transpose_last(
        const float* __restrict__ G, __hip_bfloat16* __restrict__ tB) {
    __shared__ float t[32][33];
    const int j  = blockIdx.z;
    const int i0 = blockIdx.x * 32, l0 = blockIdx.y * 32;
    #pragma unroll
    for (int q = 0; q < 4; ++q) {
        int i = i0 + threadIdx.y + q * 8;
        int l = l0 + threadIdx.x;
        t[threadIdx.y + q * 8][threadIdx.x] = G[(size_t)i * (PP * OUTD) + (size_t)j * OUTD + l];
    }
    __syncthreads();
    #pragma unroll
    for (int q = 0; q < 4; ++q) {
        int l = l0 + threadIdx.y + q * 8;
        int i = i0 + threadIdx.x;
        tB[(size_t)l * KK + (size_t)j * RR + i] =
            __float2bfloat16(tanhf(t[threadIdx.x][threadIdx.y + q * 8]));
    }
}

// ---------------------------------------------------------------------------
// First core: res0[b,r] = sum_j tanh(G0[j,r]) * z[b,0]^j  -> bf16
// ---------------------------------------------------------------------------
__global__ __launch_bounds__(512) void tt_first(
        const float* __restrict__ z, const float* __restrict__ G0,
        __hip_bfloat16* __restrict__ res0) {
    __shared__ float sg[PP * RR];
    const int b = blockIdx.x;
    for (int x = threadIdx.x; x < PP * RR; x += 512) sg[x] = tanhf(G0[x]);
    __syncthreads();
    const float z0 = z[(size_t)b * DD + 0];
    const int r = threadIdx.x;
    float p = 1.0f, acc = 0.0f;
    #pragma unroll
    for (int j = 0; j < PP; ++j) { acc += sg[j * RR + r] * p; p *= z0; }
    res0[(size_t)b * RR + r] = __float2bfloat16(acc);
}

// ---------------------------------------------------------------------------
// Mid-core Horner GEMM, A resident in registers, 2-barrier K-loop.
//   grid 512 (1D): n_blk = bid & 3 (XCD-pinned B-column), m_blk = bid >> 2.
//   256 threads = 4 waves, wave tile 32x64 (2x2 over 64x128 block tile).
//   Each wave loads its 32x512 A-panel ONCE into 128 VGPRs. Horner over
//   j = 9..0: per K-tile stage B (16KB) -> sync -> ds_read+MFMA -> sync.
//   NOTE: t-loop MUST be fully unrolled — with `#pragma unroll 1` the a[]
//   index becomes dynamic and the compiler demotes a[] to scratch
//   (round 4: VGPR=56, 67 MB scratch writes, 155 µs vs expected 40).
// ---------------------------------------------------------------------------
__global__ __launch_bounds__(256, 2) void tt_gemm_ar(
        const __hip_bfloat16* __restrict__ resin,   // [8192][512] bf16
        const __hip_bfloat16* __restrict__ tB,      // [512][5120] bf16 (n-major)
        __hip_bfloat16* __restrict__ resout,        // [8192][512] bf16
        const float* __restrict__ z, int d) {
    __shared__ __hip_bfloat16 sB[128 * 64];   // 16 KB

    const int tid  = threadIdx.x;
    const int lane = tid & 63;
    const int wave = tid >> 6;
    const int bid  = blockIdx.x;
    const int n0 = (bid & 3) * 128;
    const int m0 = (bid >> 2) * 64;
    const int wm = (wave >> 1) * 32;
    const int wn = (wave & 1) * 64;
    const int r16  = lane & 15;
    const int quad = lane >> 4;

    // ---- A resident in VGPRs: a[sm*16 + t*2 + ks] (frag layout) ----
    bf16x8 a[32];
    #pragma unroll
    for (int sm = 0; sm < 2; ++sm)
        #pragma unroll
        for (int t2 = 0; t2 < 16; ++t2)
            a[sm * 16 + t2] = *(const bf16x8*)(
                resin + (size_t)(m0 + wm + sm * 16 + r16) * RR + t2 * 32 + quad * 8);

    // ---- per-lane Horner row scales (C/D rows: wm + sm*16 + quad*4 + r) ----
    float zr[8];
    #pragma unroll
    for (int sm = 0; sm < 2; ++sm)
        #pragma unroll
        for (int r = 0; r < 4; ++r)
            zr[sm * 4 + r] = z[(size_t)(m0 + wm + sm * 16 + quad * 4 + r) * DD + d];

    f32x4 acc[2][4];
    #pragma unroll
    for (int sm = 0; sm < 2; ++sm)
        #pragma unroll
        for (int sn = 0; sn < 4; ++sn) acc[sm][sn] = f32x4{0.f, 0.f, 0.f, 0.f};

    // staging lane roles (swizzle verified 0-conflict in rounds 1-2)
    const int asrow = lane >> 3;
    const int acsw  = ((lane & 7) ^ asrow) * 8;

    #pragma unroll 1
    for (int p = 0; p < 10; ++p) {
        const int j = 9 - p;
        if (p) {
            #pragma unroll
            for (int sm = 0; sm < 2; ++sm)
                #pragma unroll
                for (int sn = 0; sn < 4; ++sn)
                    #pragma unroll
                    for (int r = 0; r < 4; ++r)
                        acc[sm][sn][r] *= zr[sm * 4 + r];
        }
        #pragma unroll
        for (int t = 0; t < 8; ++t) {
            const size_t koff = (size_t)j * RR + t * 64;
            // ---- stage B tile: 16 chunks of 8 rows x 128B, 4 per wave ----
            #pragma unroll
            for (int q = 0; q < 4; ++q) {
                const int c = wave * 4 + q;
                gload_lds16(tB + (size_t)(n0 + c * 8 + asrow) * KK + koff + acsw,
                            sB + c * 512 + lane * 8);
            }
            __syncthreads();
            // ---- compute: 2 K32 steps, A from registers ----
            #pragma unroll
            for (int ks = 0; ks < 2; ++ks) {
                const int q4 = ks * 4 + quad;
                bf16x8 bv[4];
                #pragma unroll
                for (int sn = 0; sn < 4; ++sn) {
                    const int row = wn + sn * 16 + r16;
                    bv[sn] = *(const bf16x8*)(sB + row * 64 + ((q4 ^ (row & 7)) << 3));
                }
                #pragma unroll
                for (int sm = 0; sm < 2; ++sm)
                    #pragma unroll
                    for (int sn = 0; sn < 4; ++sn)
                        acc[sm][sn] = __builtin_amdgcn_mfma_f32_16x16x32_bf16(
                            a[sm * 16 + t * 2 + ks], bv[sn], acc[sm][sn], 0, 0, 0);
            }
            __syncthreads();
        }
    }

    // ---- epilogue: bf16 store, C/D layout col=lane&15, row=quad*4+reg ----
    #pragma unroll
    for (int sm = 0; sm < 2; ++sm)
        #pragma unroll
        for (int sn = 0; sn < 4; ++sn)
            #pragma unroll
            for (int r = 0; r < 4; ++r)
                resout[(size_t)(m0 + wm + sm * 16 + quad * 4 + r) * RR
                       + n0 + wn + sn * 16 + r16] = __float2bfloat16(acc[sm][sn][r]);
}

// ---------------------------------------------------------------------------
// Last core (N=64): j-split GEMM, partial per j, epilogue scales by zb^j.
// grid (10, 64): x = j, BN=64, single panel. (Round-2 verified structure.)
// ---------------------------------------------------------------------------
template <int BN, int NPAN, bool LAST>
__global__ __launch_bounds__(256, 2) void tt_gemm_h(
        const __hip_bfloat16* __restrict__ resin,
        const __hip_bfloat16* __restrict__ tB,
        float* __restrict__ outp,
        const float* __restrict__ z, int d) {
    constexpr int BM = 128, BK = 64;
    constexpr int SN = BN / 32;
    constexpr int BCPW = (BN / 8) / 4;

    __shared__ __hip_bfloat16 sA[BM * BK];
    __shared__ __hip_bfloat16 sB[BN * BK];

    const int tid  = threadIdx.x;
    const int lane = tid & 63;
    const int wave = tid >> 6;
    const int m0 = blockIdx.y * BM;

    int n0, jtop, jbot;
    if (LAST) {
        n0 = 0; jtop = jbot = blockIdx.x;
        outp += (size_t)blockIdx.x * ((size_t)BB * OUTD);
    } else {
        n0 = (blockIdx.x >> 1) * BN;
        const int s = blockIdx.x & 1;
        jtop = 8 + s; jbot = s;
        outp += (size_t)s * ((size_t)BB * RR);
    }

    const int wm = (wave >> 1) * 64;
    const int wn = (wave & 1) * (BN / 2);
    const int rq = (lane >> 4) * 4;

    const int asrow = lane >> 3;
    const int acswz = ((lane & 7) ^ asrow) * 8;

    f32x4 acc[4][SN];
    #pragma unroll
    for (int a = 0; a < 4; ++a)
        #pragma unroll
        for (int b = 0; b < SN; ++b) acc[a][b] = f32x4{0.f, 0.f, 0.f, 0.f};

    #pragma unroll 1
    for (int pan = 0; pan < NPAN; ++pan) {
        const int j = jtop - 2 * pan;
        const size_t kb0 = (size_t)j * RR;

        #pragma unroll 1
        for (int kt = 0; kt < 8; ++kt) {
            const int kc = kt * 64;
            #pragma unroll
            for (int q = 0; q < 4; ++q) {
                const int ch = wave * 4 + q;
                gload_lds16(resin + (size_t)(m0 + ch * 8 + asrow) * RR + kc + acswz,
                            sA + ch * 512 + lane * 8);
            }
            #pragma unroll
            for (int q = 0; q < BCPW; ++q) {
                const int ch = wave * BCPW + q;
                gload_lds16(tB + (size_t)(n0 + ch * 8 + asrow) * KK + kb0 + kc + acswz,
                            sB + ch * 512 + lane * 8);
            }
            __syncthreads();

            #pragma unroll
            for (int ks = 0; ks < 2; ++ks) {
                const int q4 = ks * 4 + (lane >> 4);
                bf16x8 av[4], bv[SN];
                #pragma unroll
                for (int s = 0; s < 4; ++s) {
                    const int row = wm + s * 16 + (lane & 15);
                    av[s] = *(const bf16x8*)(sA + row * 64 + ((q4 ^ (row & 7)) << 3));
                }
                #pragma unroll
                for (int s = 0; s < SN; ++s) {
                    const int row = wn + s * 16 + (lane & 15);
                    bv[s] = *(const bf16x8*)(sB + row * 64 + ((q4 ^ (row & 7)) << 3));
                }
                #pragma unroll
                for (int sm = 0; sm < 4; ++sm)
                    #pragma unroll
                    for (int sn = 0; sn < SN; ++sn)
                        acc[sm][sn] = __builtin_amdgcn_mfma_f32_16x16x32_bf16(
                            av[sm], bv[sn], acc[sm][sn], 0, 0, 0);
            }
            __syncthreads();
        }
    }

    const int col = lane & 15;
    #pragma unroll
    for (int sm = 0; sm < 4; ++sm) {
        float zsc[4];
        #pragma unroll
        for (int r = 0; r < 4; ++r) {
            const int row = m0 + wm + sm * 16 + rq + r;
            const float zb = z[(size_t)row * DD + d];
            float p = 1.0f;
            for (int t = 0; t < jbot; ++t) p *= zb;
            zsc[r] = p;
        }
        #pragma unroll
        for (int sn = 0; sn < SN; ++sn)
            #pragma unroll
            for (int r = 0; r < 4; ++r) {
                const int grow = m0 + wm + sm * 16 + rq + r;
                const int gcol = n0 + wn + sn * 16 + col;
                outp[(size_t)grow * (LAST ? OUTD : RR) + gcol] = acc[sm][sn][r] * zsc[r];
            }
    }
}

// ---------------------------------------------------------------------------
// out[b,l] = sum_{s<10} parts[s][b][l]
// ---------------------------------------------------------------------------
__global__ __launch_bounds__(256) void reduce10(
        const float* __restrict__ p, float* __restrict__ o) {
    const size_t i = ((size_t)blockIdx.x * 256 + threadIdx.x) * 4;
    f32x4 s = f32x4{0.f, 0.f, 0.f, 0.f};
    #pragma unroll
    for (int q = 0; q < 10; ++q)
        s += *(const f32x4*)(p + (size_t)q * (BB * OUTD) + i);
    *(f32x4*)(o + i) = s;
}

// ---------------------------------------------------------------------------
extern "C" void kernel_launch(void* const* d_in, const int* in_sizes, int n_in,
                              void* d_out, int out_size, void* d_ws, size_t ws_size,
                              hipStream_t stream) {
    const float* z     = (const float*)d_in[0];
    const float* G0    = (const float*)d_in[1];
    const float* Gmid  = (const float*)d_in[2];
    const float* Glast = (const float*)d_in[3];
    float* out = (float*)d_out;

    char* ws = (char*)d_ws;
    __hip_bfloat16* resX = (__hip_bfloat16*)ws;                          // 8 MB
    __hip_bfloat16* resY = (__hip_bfloat16*)(ws + ((size_t)8 << 20));    // 8 MB
    float* LP            = (float*)(ws + ((size_t)16 << 20));            // 20 MB (last partials)
    __hip_bfloat16* tBmid  = (__hip_bfloat16*)(ws + ((size_t)48 << 20)); // 31.5 MB
    __hip_bfloat16* tBlast = (__hip_bfloat16*)(ws + ((size_t)80 << 20)); // 0.64 MB

    tanh_transpose_mid <<<dim3(16, 16, 60), dim3(32, 8), 0, stream>>>(Gmid,  tBmid);
    tanh_transpose_last<<<dim3(16, 2, 10),  dim3(32, 8), 0, stream>>>(Glast, tBlast);
    tt_first<<<BB, 512, 0, stream>>>(z, G0, resX);

    __hip_bfloat16* rin = resX;
    __hip_bfloat16* rnext = resY;
    for (int c = 0; c < 6; ++c) {
        tt_gemm_ar<<<dim3(512), 256, 0, stream>>>(
            rin, tBmid + (size_t)c * RR * KK, rnext, z, c + 1);
        __hip_bfloat16* t = rin; rin = rnext; rnext = t;
    }
    tt_gemm_h<64, 1, true><<<dim3(10, BB / 128), 256, 0, stream>>>(
        rin, tBlast, LP, z, 7);
    reduce10<<<dim3((BB * OUTD) / 1024), 256, 0, stream>>>(LP, out);
}